// Round 16
// baseline (99.674 us; speedup 1.0000x reference)
//
#include <hip/hip_runtime.h>

#define NB  32
#define NTC 2048
#define NTQ 256
#define ND  256

// ws layout (floats):
// hp2[32][32][260] @0 ; h[32][256] @266240 ; q2[32][256] @274432 ;
// Qbf(bf16) @282624f ; Qt(bf16) @+1M floats
#define HP2_OFF 0
#define H_OFF   266240
#define Q2_OFF  274432
#define QBF_OFF 282624
#define QT_OFF  (282624 + 1048576)

typedef __attribute__((ext_vector_type(8))) short short8v;
typedef __attribute__((ext_vector_type(4))) float float4v;
typedef unsigned int u32;

static __device__ inline short f2bf(float f) {
  union { float f; unsigned u; } v; v.f = f;
  unsigned r = v.u + 0x7FFFu + ((v.u >> 16) & 1u);
  return (short)(r >> 16);
}

static __device__ inline void gload_lds16(const short* g, short* l) {
  __builtin_amdgcn_global_load_lds(
      (const __attribute__((address_space(1))) u32*)g,
      (__attribute__((address_space(3))) u32*)l, 16, 0, 0);
}

static __device__ inline void nt_store4(float* p, float4 v) {
  float4v t;
  t[0] = v.x; t[1] = v.y; t[2] = v.z; t[3] = v.w;
  __builtin_nontemporal_store(t, (float4v*)p);
}
static __device__ inline void nt_store(float* p, float v) {
  __builtin_nontemporal_store(v, p);
}

// K0: per (b, 32-row q-chunk): Qbf = bf16(Q); Qt = bf16(Q)^T; q2 = Q.w2
__global__ __launch_bounds__(256) void k0_prep(const float* __restrict__ qry,
                                               const float* __restrict__ w,
                                               float* __restrict__ q2_ws,
                                               short* __restrict__ Qbf,
                                               short* __restrict__ Qt) {
  __shared__ float sRed[8][32];
  const int tid = threadIdx.x;
  const int b = blockIdx.x >> 3;
  const int q0 = (blockIdx.x & 7) << 5;
  const int q = tid & 31;
  const int dc = tid >> 5;
  const float* src = qry + (((size_t)b * NTQ) + q0 + q) * ND + dc * 32;
  const float* w2p = w + ND + dc * 32;

  float vals[32];
  float part = 0.f;
  #pragma unroll
  for (int i = 0; i < 8; ++i) {
    float4 v = *(const float4*)(src + 4 * i);
    float4 u = *(const float4*)(w2p + 4 * i);
    part += v.x*u.x + v.y*u.y + v.z*u.z + v.w*u.w;
    vals[4*i] = v.x; vals[4*i+1] = v.y; vals[4*i+2] = v.z; vals[4*i+3] = v.w;
  }
  short pk[32];
  #pragma unroll
  for (int i = 0; i < 32; ++i) pk[i] = f2bf(vals[i]);

  short* dst = Qbf + ((size_t)b * NTQ + q0 + q) * ND + dc * 32;
  #pragma unroll
  for (int i = 0; i < 4; ++i) *(short8v*)(dst + 8 * i) = *(short8v*)(pk + 8 * i);
  short* dstT = Qt + (size_t)b * NTQ * ND + q0 + q;
  #pragma unroll
  for (int i = 0; i < 32; ++i) dstT[(size_t)(dc * 32 + i) * NTQ] = pk[i];

  part += __shfl_xor(part, 32);
  if ((tid & 32) == 0) sRed[dc][q] = part;
  __syncthreads();
  if (tid < 32) {
    float s = sRed[0][tid] + sRed[2][tid] + sRed[4][tid] + sRed[6][tid];
    q2_ws[b * NTQ + q0 + tid] = s;
  }
}

// K1 (r9 structure): swapped-operand phase 1 with inline G0=C (nt stores),
// in-register P, phase-2 r9 form (nt sector-coalesced scalar stores),
// tile-partial h -> hp2 (cacheable).
__global__ __launch_bounds__(256, 4) void k1_main(const float* __restrict__ ctx,
                                                  const float* __restrict__ w,
                                                  const short* __restrict__ Qbf,
                                                  const short* __restrict__ Qt,
                                                  const float* __restrict__ q2_ws,
                                                  float* __restrict__ hp2,
                                                  float* __restrict__ G) {
  __shared__ __align__(16) short sStage[2][256 * 32];    // 2 x 16KB
  __shared__ __align__(16) float sW[512];                // w1 | w3
  __shared__ __align__(16) float sQ2[256];               // q2 tile
  __shared__ __align__(16) float sHall[4][256];          // per-wave partial h
  __shared__ float sRedM[4], sRedZ[4];

  const int tid  = threadIdx.x;
  const int wv   = tid >> 6;
  const int lane = tid & 63;
  const int g    = lane >> 4;
  const int li   = lane & 15;
  const int bid  = blockIdx.x;
  const int obid = (bid & 7) * 128 + (bid >> 3);   // XCD-bijective swizzle
  const int b    = obid >> 5;
  const int tile = obid & 31;
  const int t0   = tile << 6;

  const float* __restrict__ ctxB = ctx + ((size_t)b * NTC + t0) * ND;
  const short* __restrict__ Qb   = Qbf + (size_t)b * NTQ * ND;
  const short* __restrict__ Qtb  = Qt  + (size_t)b * NTQ * ND;

  const int srow = 64 * wv + (lane >> 2);
  const int sblk = lane & 3;

  #define STAGE(buf, src, c0)                                                   \
    { _Pragma("unroll")                                                         \
      for (int j = 0; j < 4; ++j) {                                             \
        const int row_ = srow + 16 * j;                                         \
        const int gi_  = sblk ^ ((row_ >> 1) & 3);                              \
        gload_lds16((src) + (size_t)row_ * 256 + (c0) + 8 * gi_,                \
                    &sStage[buf][wv * 2048 + j * 512]);                         \
      } }

  #define STAGE2(buf, cc)                                                       \
    { _Pragma("unroll")                                                         \
      for (int j = 0; j < 4; ++j) {                                             \
        const int slot_ = (wv * 4 + j) * 64 + lane;                             \
        const int row_  = slot_ >> 5;                                           \
        const int gr_   = slot_ & 31;                                           \
        gload_lds16(Qtb + (size_t)(32 * (cc) + row_) * 256 + 8 * (gr_ ^ (row_ & 7)), \
                    &sStage[buf][wv * 2048 + j * 512]);                         \
      } }

  float4v acc[16];
  #pragma unroll
  for (int n = 0; n < 16; ++n) acc[n] = (float4v)0.f;
  float s1part = 0.f;

  // ---- prologue ----
  if (tid < 64)       *(float4*)(sW + 4 * tid) = *(const float4*)(w + 4 * tid);
  else if (tid < 128) *(float4*)(sW + 4 * tid) = *(const float4*)(w + 512 + 4 * tid - 256);
  else if (tid < 192) *(float4*)(sQ2 + 4 * (tid - 128)) = *(const float4*)(q2_ws + b * NTQ + 4 * (tid - 128));
  STAGE(0, Qb, 0);
  const float* arow = ctxB + (size_t)(16 * wv + li) * ND + 8 * g;
  float4 Ac0 = *(const float4*)(arow);
  float4 Ac1 = *(const float4*)(arow + 4);
  asm volatile("s_waitcnt vmcnt(0) lgkmcnt(0)" ::: "memory");
  __builtin_amdgcn_s_barrier();
  __builtin_amdgcn_sched_barrier(0);

  const size_t gb0 = ((size_t)b * NTC + t0 + 16 * wv + li) * 1024 + 8 * g;

  // ---- Phase 1: chunks 0..7; acc[n][r] = S[t=16wv+li][q=16n+4g+r] ----
  #pragma unroll
  for (int c = 0; c < 8; ++c) {
    float4 u0 = *(const float4*)(sW + 32 * c + 8 * g);
    float4 u1 = *(const float4*)(sW + 32 * c + 8 * g + 4);
    float4 v0 = *(const float4*)(sW + 256 + 32 * c + 8 * g);
    float4 v1 = *(const float4*)(sW + 256 + 32 * c + 8 * g + 4);
    s1part += Ac0.x*u0.x + Ac0.y*u0.y + Ac0.z*u0.z + Ac0.w*u0.w
            + Ac1.x*u1.x + Ac1.y*u1.y + Ac1.z*u1.z + Ac1.w*u1.w;
    short8v af;
    af[0]=f2bf(Ac0.x*v0.x); af[1]=f2bf(Ac0.y*v0.y); af[2]=f2bf(Ac0.z*v0.z); af[3]=f2bf(Ac0.w*v0.w);
    af[4]=f2bf(Ac1.x*v1.x); af[5]=f2bf(Ac1.y*v1.y); af[6]=f2bf(Ac1.z*v1.z); af[7]=f2bf(Ac1.w*v1.w);
    __builtin_amdgcn_sched_barrier(0);
    float4 An0, An1;
    if (c < 7) {
      An0 = *(const float4*)(arow + 32 * (c + 1));
      An1 = *(const float4*)(arow + 32 * (c + 1) + 4);
    }
    __builtin_amdgcn_sched_barrier(0);
    if (c < 7) { STAGE((c + 1) & 1, Qb, 32 * (c + 1)); }
    else       { STAGE2(0, 0); }
    __builtin_amdgcn_sched_barrier(0);
    if (c == 7) asm volatile("s_waitcnt vmcnt(6)" ::: "memory");
    else        asm volatile("s_waitcnt vmcnt(8)" ::: "memory");
    __builtin_amdgcn_s_barrier();
    __builtin_amdgcn_sched_barrier(0);
    const short* sb = sStage[c & 1];
    #pragma unroll
    for (int n = 0; n < 16; ++n) {
      const int row = 16 * n + li;
      short8v bb = *(const short8v*)(sb + row * 32 + 8 * (g ^ ((row >> 1) & 3)));
      acc[n] = __builtin_amdgcn_mfma_f32_16x16x32_bf16(bb, af, acc[n], 0, 0, 0);  // SWAPPED
    }
    nt_store4(G + gb0 + 32 * c,     Ac0);   // G0 = C (nt, spread writes)
    nt_store4(G + gb0 + 32 * c + 4, Ac1);
    __builtin_amdgcn_sched_barrier(0);
    __builtin_amdgcn_s_barrier();
    __builtin_amdgcn_sched_barrier(0);
    Ac0 = An0; Ac1 = An1;
  }

  // ---- softmax: lane owns row t = 16wv+li ----
  s1part += __shfl_xor(s1part, 16);
  s1part += __shfl_xor(s1part, 32);
  #pragma unroll
  for (int n = 0; n < 16; ++n) {
    float4 qv = *(const float4*)(sQ2 + 16 * n + 4 * g);
    acc[n][0] += s1part + qv.x;
    acc[n][1] += s1part + qv.y;
    acc[n][2] += s1part + qv.z;
    acc[n][3] += s1part + qv.w;
  }
  float mx = acc[0][0];
  #pragma unroll
  for (int n = 0; n < 16; ++n)
    #pragma unroll
    for (int r = 0; r < 4; ++r) mx = fmaxf(mx, acc[n][r]);
  mx = fmaxf(mx, __shfl_xor(mx, 16));
  mx = fmaxf(mx, __shfl_xor(mx, 32));
  float z = 0.f;
  #pragma unroll
  for (int n = 0; n < 16; ++n)
    #pragma unroll
    for (int r = 0; r < 4; ++r) { float e = __expf(acc[n][r] - mx); acc[n][r] = e; z += e; }
  z += __shfl_xor(z, 16);
  z += __shfl_xor(z, 32);
  const float inv = 1.0f / z;

  // ---- tile b_t stats ----
  float tm = mx;
  tm = fmaxf(tm, __shfl_xor(tm, 1));
  tm = fmaxf(tm, __shfl_xor(tm, 2));
  tm = fmaxf(tm, __shfl_xor(tm, 4));
  tm = fmaxf(tm, __shfl_xor(tm, 8));
  if (lane == 0) sRedM[wv] = tm;
  __builtin_amdgcn_sched_barrier(0);
  asm volatile("s_waitcnt lgkmcnt(0)" ::: "memory");
  __builtin_amdgcn_s_barrier();
  __builtin_amdgcn_sched_barrier(0);
  const float Mloc = fmaxf(fmaxf(sRedM[0], sRedM[1]), fmaxf(sRedM[2], sRedM[3]));
  const float wgt = __expf(mx - Mloc);     // weight of own t-row (t = 16wv+li)
  float zp = wgt;
  zp += __shfl_xor(zp, 1);
  zp += __shfl_xor(zp, 2);
  zp += __shfl_xor(zp, 4);
  zp += __shfl_xor(zp, 8);
  if (lane == 0) sRedZ[wv] = zp;
  float wgtRow[4];
  #pragma unroll
  for (int r = 0; r < 4; ++r) wgtRow[r] = __shfl(wgt, 4 * g + r);

  // ---- pack P; build phase-2 A-fragments by cross-g shuffle ----
  int pkx[16], pky[16];
  #pragma unroll
  for (int n = 0; n < 16; ++n) {
    pkx[n] = (int)(u32)(unsigned short)f2bf(acc[n][0] * inv)
           | ((int)(u32)(unsigned short)f2bf(acc[n][1] * inv) << 16);
    pky[n] = (int)(u32)(unsigned short)f2bf(acc[n][2] * inv)
           | ((int)(u32)(unsigned short)f2bf(acc[n][3] * inv) << 16);
  }
  const int srcLow  = ((g & 1) << 5) + li;
  const int srcHigh = srcLow + 16;
  const bool hiSel  = (g >= 2);
  short8v a2f[8];
  #pragma unroll
  for (int ks = 0; ks < 8; ++ks) {
    int eL0 = __shfl(pkx[2 * ks],     srcLow);
    int eL1 = __shfl(pky[2 * ks],     srcLow);
    int oL0 = __shfl(pkx[2 * ks + 1], srcLow);
    int oL1 = __shfl(pky[2 * ks + 1], srcLow);
    int eH0 = __shfl(pkx[2 * ks],     srcHigh);
    int eH1 = __shfl(pky[2 * ks],     srcHigh);
    int oH0 = __shfl(pkx[2 * ks + 1], srcHigh);
    int oH1 = __shfl(pky[2 * ks + 1], srcHigh);
    union { int i[4]; short8v s; } u;
    u.i[0] = hiSel ? oL0 : eL0;
    u.i[1] = hiSel ? oL1 : eL1;
    u.i[2] = hiSel ? oH0 : eH0;
    u.i[3] = hiSel ? oH1 : eH1;
    a2f[ks] = u.s;
  }

  // ---- Phase 2 (d-major, r9 form): uacc rows t=16wv+4g+r, d={li,16+li}+32cc ----
  #pragma unroll
  for (int cc = 0; cc < 8; ++cc) {
    if (cc < 7) { STAGE2((cc + 1) & 1, cc + 1); }
    __builtin_amdgcn_sched_barrier(0);
    if (cc == 0)      asm volatile("s_waitcnt vmcnt(2)"  ::: "memory");  // 4 oldest (STAGE2(0)) retired
    else if (cc == 7) asm volatile("s_waitcnt vmcnt(24)" ::: "memory");
    else              asm volatile("s_waitcnt vmcnt(28)" ::: "memory");
    __builtin_amdgcn_s_barrier();
    __builtin_amdgcn_sched_barrier(0);
    const short* sb = sStage[cc & 1];
    float4v uacc0 = (float4v)0.f, uacc1 = (float4v)0.f;
    #pragma unroll
    for (int ks = 0; ks < 8; ++ks) {
      short8v b0 = *(const short8v*)(sb + (li)      * 256 + 8 * ((4 * ks + g) ^ (li & 7)));
      short8v b1 = *(const short8v*)(sb + (16 + li) * 256 + 8 * ((4 * ks + g) ^ (li & 7)));
      uacc0 = __builtin_amdgcn_mfma_f32_16x16x32_bf16(a2f[ks], b0, uacc0, 0, 0, 0);
      uacc1 = __builtin_amdgcn_mfma_f32_16x16x32_bf16(a2f[ks], b1, uacc1, 0, 0, 0);
    }
    __builtin_amdgcn_sched_barrier(0);
    __builtin_amdgcn_s_barrier();
    __builtin_amdgcn_sched_barrier(0);
    float hc0 = 0.f, hc1 = 0.f;
    #pragma unroll
    for (int r = 0; r < 4; ++r) {
      const int trow = 16 * wv + 4 * g + r;
      const size_t gb = ((size_t)b * NTC + t0 + trow) * 1024 + 32 * cc;
      const float* cp = ctxB + (size_t)trow * ND + 32 * cc;
      const float c0 = cp[li];
      const float c1 = cp[16 + li];
      const float uu0 = uacc0[r];
      const float uu1 = uacc1[r];
      nt_store(G + gb + 256 + li,      uu0);
      nt_store(G + gb + 256 + 16 + li, uu1);
      nt_store(G + gb + 512 + li,      c0 * uu0);
      nt_store(G + gb + 512 + 16 + li, c1 * uu1);
      hc0 += wgtRow[r] * c0;
      hc1 += wgtRow[r] * c1;
    }
    hc0 += __shfl_xor(hc0, 16); hc0 += __shfl_xor(hc0, 32);
    hc1 += __shfl_xor(hc1, 16); hc1 += __shfl_xor(hc1, 32);
    if (g == 0) {
      sHall[wv][32 * cc + li]      = hc0;
      sHall[wv][32 * cc + 16 + li] = hc1;
    }
  }

  // ---- hp2 write (cacheable — re-read by k2h) ----
  __syncthreads();
  float* hp = hp2 + (size_t)(b * 32 + tile) * 260;
  {
    const int d = tid & 255;
    float ph = sHall[0][d] + sHall[1][d] + sHall[2][d] + sHall[3][d];
    hp[d] = ph;
  }
  if (tid == 0) {
    hp[256] = Mloc;
    hp[257] = sRedZ[0] + sRedZ[1] + sRedZ[2] + sRedZ[3];
  }
  #undef STAGE
  #undef STAGE2
}

// K2h: per batch, combine 32 tile partials -> h[b][256]
__global__ __launch_bounds__(256) void k2h(const float* __restrict__ hp2,
                                           float* __restrict__ h_ws) {
  __shared__ float sM2[32], sZ2[32];
  const int b = blockIdx.x;
  const int tid = threadIdx.x;
  if (tid < 32) {
    sM2[tid] = hp2[(size_t)(b * 32 + tid) * 260 + 256];
    sZ2[tid] = hp2[(size_t)(b * 32 + tid) * 260 + 257];
  }
  __syncthreads();
  float M = -1e30f;
  #pragma unroll
  for (int i = 0; i < 32; ++i) M = fmaxf(M, sM2[i]);
  float Z = 0.f;
  float a = 0.f;
  #pragma unroll
  for (int i = 0; i < 32; ++i) {
    float e = __expf(sM2[i] - M);
    Z += sZ2[i] * e;
    a += hp2[(size_t)(b * 32 + i) * 260 + tid] * e;
  }
  h_ws[b * 256 + tid] = a / Z;
}

// K3: G[...,768:1024] = C * h[b,:]   (nt stores; C read should be L3-hot)
__global__ __launch_bounds__(256) void k3_epi(const float* __restrict__ ctx,
                                              const float* __restrict__ h_ws,
                                              float* __restrict__ G) {
  size_t f = (size_t)blockIdx.x * 256 + threadIdx.x;
  size_t e = f * 4;
  int d = (int)(e & 255);
  size_t bt = e >> 8;
  int b = (int)(bt >> 11);
  float4 c = *(const float4*)(ctx + e);
  float4 h = *(const float4*)(h_ws + b * ND + d);
  nt_store4(G + bt * 1024 + 768 + d,
            make_float4(c.x * h.x, c.y * h.y, c.z * h.z, c.w * h.w));
}

extern "C" void kernel_launch(void* const* d_in, const int* in_sizes, int n_in,
                              void* d_out, int out_size, void* d_ws, size_t ws_size,
                              hipStream_t stream) {
  const float* ctx = (const float*)d_in[0];
  const float* qry = (const float*)d_in[1];
  const float* w   = (const float*)d_in[2];
  float* G  = (float*)d_out;
  float* ws = (float*)d_ws;
  float* hp2   = ws + HP2_OFF;
  float* h_ws  = ws + H_OFF;
  float* q2_ws = ws + Q2_OFF;
  short* Qbf = (short*)(ws + QBF_OFF);
  short* Qt  = (short*)(ws + QT_OFF);

  k0_prep<<<NB * 8, 256, 0, stream>>>(qry, w, q2_ws, Qbf, Qt);
  k1_main<<<NB * (NTC / 64), 256, 0, stream>>>(ctx, w, Qbf, Qt, q2_ws, hp2, G);
  k2h<<<NB, 256, 0, stream>>>(hp2, h_ws);
  k3_epi<<<16384, 256, 0, stream>>>(ctx, h_ws, G);
}

// Round 17
// 94.668 us; speedup vs baseline: 1.0529x; 1.0529x over previous
//
#include <hip/hip_runtime.h>

#define NB  32
#define NTC 2048
#define NTQ 256
#define ND  256

// ws layout (floats):
// hp2[32][32][260] @0 ; h[32][256] @266240 ; q2[32][256] @274432 ;
// Qbf(bf16) @282624f ; Qt(bf16) @+1M floats
#define HP2_OFF 0
#define H_OFF   266240
#define Q2_OFF  274432
#define QBF_OFF 282624
#define QT_OFF  (282624 + 1048576)

typedef __attribute__((ext_vector_type(8))) short short8v;
typedef __attribute__((ext_vector_type(4))) float float4v;
typedef unsigned int u32;

static __device__ inline short f2bf(float f) {
  union { float f; unsigned u; } v; v.f = f;
  unsigned r = v.u + 0x7FFFu + ((v.u >> 16) & 1u);
  return (short)(r >> 16);
}

static __device__ inline void gload_lds16(const short* g, short* l) {
  __builtin_amdgcn_global_load_lds(
      (const __attribute__((address_space(1))) u32*)g,
      (__attribute__((address_space(3))) u32*)l, 16, 0, 0);
}

// K0: per (b, 32-row q-chunk): Qbf = bf16(Q); Qt = bf16(Q)^T; q2 = Q.w2
__global__ __launch_bounds__(256) void k0_prep(const float* __restrict__ qry,
                                               const float* __restrict__ w,
                                               float* __restrict__ q2_ws,
                                               short* __restrict__ Qbf,
                                               short* __restrict__ Qt) {
  __shared__ float sRed[8][32];
  const int tid = threadIdx.x;
  const int b = blockIdx.x >> 3;
  const int q0 = (blockIdx.x & 7) << 5;
  const int q = tid & 31;
  const int dc = tid >> 5;
  const float* src = qry + (((size_t)b * NTQ) + q0 + q) * ND + dc * 32;
  const float* w2p = w + ND + dc * 32;

  float vals[32];
  float part = 0.f;
  #pragma unroll
  for (int i = 0; i < 8; ++i) {
    float4 v = *(const float4*)(src + 4 * i);
    float4 u = *(const float4*)(w2p + 4 * i);
    part += v.x*u.x + v.y*u.y + v.z*u.z + v.w*u.w;
    vals[4*i] = v.x; vals[4*i+1] = v.y; vals[4*i+2] = v.z; vals[4*i+3] = v.w;
  }
  short pk[32];
  #pragma unroll
  for (int i = 0; i < 32; ++i) pk[i] = f2bf(vals[i]);

  short* dst = Qbf + ((size_t)b * NTQ + q0 + q) * ND + dc * 32;
  #pragma unroll
  for (int i = 0; i < 4; ++i) *(short8v*)(dst + 8 * i) = *(short8v*)(pk + 8 * i);
  short* dstT = Qt + (size_t)b * NTQ * ND + q0 + q;
  #pragma unroll
  for (int i = 0; i < 32; ++i) dstT[(size_t)(dc * 32 + i) * NTQ] = pk[i];

  part += __shfl_xor(part, 32);
  if ((tid & 32) == 0) sRed[dc][q] = part;
  __syncthreads();
  if (tid < 32) {
    float s = sRed[0][tid] + sRed[2][tid] + sRed[4][tid] + sRed[6][tid];
    q2_ws[b * NTQ + q0 + tid] = s;
  }
}

// K1 (r9 structure): swapped-operand phase 1 with inline G0=C, in-register P,
// phase-2 r9 form (sector-coalesced scalar stores), tile-partial h -> hp2.
__global__ __launch_bounds__(256, 4) void k1_main(const float* __restrict__ ctx,
                                                  const float* __restrict__ w,
                                                  const short* __restrict__ Qbf,
                                                  const short* __restrict__ Qt,
                                                  const float* __restrict__ q2_ws,
                                                  float* __restrict__ hp2,
                                                  float* __restrict__ G) {
  __shared__ __align__(16) short sStage[2][256 * 32];    // 2 x 16KB
  __shared__ __align__(16) float sW[512];                // w1 | w3
  __shared__ __align__(16) float sQ2[256];               // q2 tile
  __shared__ __align__(16) float sHall[4][256];          // per-wave partial h
  __shared__ float sRedM[4], sRedZ[4];

  const int tid  = threadIdx.x;
  const int wv   = tid >> 6;
  const int lane = tid & 63;
  const int g    = lane >> 4;
  const int li   = lane & 15;
  const int bid  = blockIdx.x;
  const int obid = (bid & 7) * 128 + (bid >> 3);   // XCD-bijective swizzle
  const int b    = obid >> 5;
  const int tile = obid & 31;
  const int t0   = tile << 6;

  const float* __restrict__ ctxB = ctx + ((size_t)b * NTC + t0) * ND;
  const short* __restrict__ Qb   = Qbf + (size_t)b * NTQ * ND;
  const short* __restrict__ Qtb  = Qt  + (size_t)b * NTQ * ND;

  const int srow = 64 * wv + (lane >> 2);
  const int sblk = lane & 3;

  #define STAGE(buf, src, c0)                                                   \
    { _Pragma("unroll")                                                         \
      for (int j = 0; j < 4; ++j) {                                             \
        const int row_ = srow + 16 * j;                                         \
        const int gi_  = sblk ^ ((row_ >> 1) & 3);                              \
        gload_lds16((src) + (size_t)row_ * 256 + (c0) + 8 * gi_,                \
                    &sStage[buf][wv * 2048 + j * 512]);                         \
      } }

  #define STAGE2(buf, cc)                                                       \
    { _Pragma("unroll")                                                         \
      for (int j = 0; j < 4; ++j) {                                             \
        const int slot_ = (wv * 4 + j) * 64 + lane;                             \
        const int row_  = slot_ >> 5;                                           \
        const int gr_   = slot_ & 31;                                           \
        gload_lds16(Qtb + (size_t)(32 * (cc) + row_) * 256 + 8 * (gr_ ^ (row_ & 7)), \
                    &sStage[buf][wv * 2048 + j * 512]);                         \
      } }

  float4v acc[16];
  #pragma unroll
  for (int n = 0; n < 16; ++n) acc[n] = (float4v)0.f;
  float s1part = 0.f;

  // ---- prologue ----
  if (tid < 64)       *(float4*)(sW + 4 * tid) = *(const float4*)(w + 4 * tid);
  else if (tid < 128) *(float4*)(sW + 4 * tid) = *(const float4*)(w + 512 + 4 * tid - 256);
  else if (tid < 192) *(float4*)(sQ2 + 4 * (tid - 128)) = *(const float4*)(q2_ws + b * NTQ + 4 * (tid - 128));
  STAGE(0, Qb, 0);
  const float* arow = ctxB + (size_t)(16 * wv + li) * ND + 8 * g;
  float4 Ac0 = *(const float4*)(arow);
  float4 Ac1 = *(const float4*)(arow + 4);
  asm volatile("s_waitcnt vmcnt(0) lgkmcnt(0)" ::: "memory");
  __builtin_amdgcn_s_barrier();
  __builtin_amdgcn_sched_barrier(0);

  const size_t gb0 = ((size_t)b * NTC + t0 + 16 * wv + li) * 1024 + 8 * g;

  // ---- Phase 1: chunks 0..7; acc[n][r] = S[t=16wv+li][q=16n+4g+r] ----
  #pragma unroll
  for (int c = 0; c < 8; ++c) {
    float4 u0 = *(const float4*)(sW + 32 * c + 8 * g);
    float4 u1 = *(const float4*)(sW + 32 * c + 8 * g + 4);
    float4 v0 = *(const float4*)(sW + 256 + 32 * c + 8 * g);
    float4 v1 = *(const float4*)(sW + 256 + 32 * c + 8 * g + 4);
    s1part += Ac0.x*u0.x + Ac0.y*u0.y + Ac0.z*u0.z + Ac0.w*u0.w
            + Ac1.x*u1.x + Ac1.y*u1.y + Ac1.z*u1.z + Ac1.w*u1.w;
    short8v af;
    af[0]=f2bf(Ac0.x*v0.x); af[1]=f2bf(Ac0.y*v0.y); af[2]=f2bf(Ac0.z*v0.z); af[3]=f2bf(Ac0.w*v0.w);
    af[4]=f2bf(Ac1.x*v1.x); af[5]=f2bf(Ac1.y*v1.y); af[6]=f2bf(Ac1.z*v1.z); af[7]=f2bf(Ac1.w*v1.w);
    __builtin_amdgcn_sched_barrier(0);
    float4 An0, An1;
    if (c < 7) {
      An0 = *(const float4*)(arow + 32 * (c + 1));
      An1 = *(const float4*)(arow + 32 * (c + 1) + 4);
    }
    __builtin_amdgcn_sched_barrier(0);
    if (c < 7) { STAGE((c + 1) & 1, Qb, 32 * (c + 1)); }
    else       { STAGE2(0, 0); }
    __builtin_amdgcn_sched_barrier(0);
    if (c == 7) asm volatile("s_waitcnt vmcnt(6)" ::: "memory");
    else        asm volatile("s_waitcnt vmcnt(8)" ::: "memory");
    __builtin_amdgcn_s_barrier();
    __builtin_amdgcn_sched_barrier(0);
    const short* sb = sStage[c & 1];
    #pragma unroll
    for (int n = 0; n < 16; ++n) {
      const int row = 16 * n + li;
      short8v bb = *(const short8v*)(sb + row * 32 + 8 * (g ^ ((row >> 1) & 3)));
      acc[n] = __builtin_amdgcn_mfma_f32_16x16x32_bf16(bb, af, acc[n], 0, 0, 0);  // SWAPPED
    }
    *(float4*)(G + gb0 + 32 * c)     = Ac0;   // G0 = C (spread writes)
    *(float4*)(G + gb0 + 32 * c + 4) = Ac1;
    __builtin_amdgcn_sched_barrier(0);
    __builtin_amdgcn_s_barrier();
    __builtin_amdgcn_sched_barrier(0);
    Ac0 = An0; Ac1 = An1;
  }

  // ---- softmax: lane owns row t = 16wv+li ----
  s1part += __shfl_xor(s1part, 16);
  s1part += __shfl_xor(s1part, 32);
  #pragma unroll
  for (int n = 0; n < 16; ++n) {
    float4 qv = *(const float4*)(sQ2 + 16 * n + 4 * g);
    acc[n][0] += s1part + qv.x;
    acc[n][1] += s1part + qv.y;
    acc[n][2] += s1part + qv.z;
    acc[n][3] += s1part + qv.w;
  }
  float mx = acc[0][0];
  #pragma unroll
  for (int n = 0; n < 16; ++n)
    #pragma unroll
    for (int r = 0; r < 4; ++r) mx = fmaxf(mx, acc[n][r]);
  mx = fmaxf(mx, __shfl_xor(mx, 16));
  mx = fmaxf(mx, __shfl_xor(mx, 32));
  float z = 0.f;
  #pragma unroll
  for (int n = 0; n < 16; ++n)
    #pragma unroll
    for (int r = 0; r < 4; ++r) { float e = __expf(acc[n][r] - mx); acc[n][r] = e; z += e; }
  z += __shfl_xor(z, 16);
  z += __shfl_xor(z, 32);
  const float inv = 1.0f / z;

  // ---- tile b_t stats ----
  float tm = mx;
  tm = fmaxf(tm, __shfl_xor(tm, 1));
  tm = fmaxf(tm, __shfl_xor(tm, 2));
  tm = fmaxf(tm, __shfl_xor(tm, 4));
  tm = fmaxf(tm, __shfl_xor(tm, 8));
  if (lane == 0) sRedM[wv] = tm;
  __builtin_amdgcn_sched_barrier(0);
  asm volatile("s_waitcnt lgkmcnt(0)" ::: "memory");
  __builtin_amdgcn_s_barrier();
  __builtin_amdgcn_sched_barrier(0);
  const float Mloc = fmaxf(fmaxf(sRedM[0], sRedM[1]), fmaxf(sRedM[2], sRedM[3]));
  const float wgt = __expf(mx - Mloc);     // weight of own t-row (t = 16wv+li)
  float zp = wgt;
  zp += __shfl_xor(zp, 1);
  zp += __shfl_xor(zp, 2);
  zp += __shfl_xor(zp, 4);
  zp += __shfl_xor(zp, 8);
  if (lane == 0) sRedZ[wv] = zp;
  float wgtRow[4];
  #pragma unroll
  for (int r = 0; r < 4; ++r) wgtRow[r] = __shfl(wgt, 4 * g + r);

  // ---- pack P; build phase-2 A-fragments by cross-g shuffle ----
  int pkx[16], pky[16];
  #pragma unroll
  for (int n = 0; n < 16; ++n) {
    pkx[n] = (int)(u32)(unsigned short)f2bf(acc[n][0] * inv)
           | ((int)(u32)(unsigned short)f2bf(acc[n][1] * inv) << 16);
    pky[n] = (int)(u32)(unsigned short)f2bf(acc[n][2] * inv)
           | ((int)(u32)(unsigned short)f2bf(acc[n][3] * inv) << 16);
  }
  const int srcLow  = ((g & 1) << 5) + li;
  const int srcHigh = srcLow + 16;
  const bool hiSel  = (g >= 2);
  short8v a2f[8];
  #pragma unroll
  for (int ks = 0; ks < 8; ++ks) {
    int eL0 = __shfl(pkx[2 * ks],     srcLow);
    int eL1 = __shfl(pky[2 * ks],     srcLow);
    int oL0 = __shfl(pkx[2 * ks + 1], srcLow);
    int oL1 = __shfl(pky[2 * ks + 1], srcLow);
    int eH0 = __shfl(pkx[2 * ks],     srcHigh);
    int eH1 = __shfl(pky[2 * ks],     srcHigh);
    int oH0 = __shfl(pkx[2 * ks + 1], srcHigh);
    int oH1 = __shfl(pky[2 * ks + 1], srcHigh);
    union { int i[4]; short8v s; } u;
    u.i[0] = hiSel ? oL0 : eL0;
    u.i[1] = hiSel ? oL1 : eL1;
    u.i[2] = hiSel ? oH0 : eH0;
    u.i[3] = hiSel ? oH1 : eH1;
    a2f[ks] = u.s;
  }

  // ---- Phase 2 (d-major, r9 form): uacc rows t=16wv+4g+r, d={li,16+li}+32cc ----
  #pragma unroll
  for (int cc = 0; cc < 8; ++cc) {
    if (cc < 7) { STAGE2((cc + 1) & 1, cc + 1); }
    __builtin_amdgcn_sched_barrier(0);
    if (cc == 0)      asm volatile("s_waitcnt vmcnt(2)"  ::: "memory");  // strict: STAGE2(0) retired
    else if (cc == 7) asm volatile("s_waitcnt vmcnt(24)" ::: "memory");
    else              asm volatile("s_waitcnt vmcnt(28)" ::: "memory");
    __builtin_amdgcn_s_barrier();
    __builtin_amdgcn_sched_barrier(0);
    const short* sb = sStage[cc & 1];
    float4v uacc0 = (float4v)0.f, uacc1 = (float4v)0.f;
    #pragma unroll
    for (int ks = 0; ks < 8; ++ks) {
      short8v b0 = *(const short8v*)(sb + (li)      * 256 + 8 * ((4 * ks + g) ^ (li & 7)));
      short8v b1 = *(const short8v*)(sb + (16 + li) * 256 + 8 * ((4 * ks + g) ^ (li & 7)));
      uacc0 = __builtin_amdgcn_mfma_f32_16x16x32_bf16(a2f[ks], b0, uacc0, 0, 0, 0);
      uacc1 = __builtin_amdgcn_mfma_f32_16x16x32_bf16(a2f[ks], b1, uacc1, 0, 0, 0);
    }
    __builtin_amdgcn_sched_barrier(0);
    __builtin_amdgcn_s_barrier();
    __builtin_amdgcn_sched_barrier(0);
    float hc0 = 0.f, hc1 = 0.f;
    #pragma unroll
    for (int r = 0; r < 4; ++r) {
      const int trow = 16 * wv + 4 * g + r;
      const size_t gb = ((size_t)b * NTC + t0 + trow) * 1024 + 32 * cc;
      const float* cp = ctxB + (size_t)trow * ND + 32 * cc;
      const float c0 = cp[li];
      const float c1 = cp[16 + li];
      const float uu0 = uacc0[r];
      const float uu1 = uacc1[r];
      G[gb + 256 + li]      = uu0;
      G[gb + 256 + 16 + li] = uu1;
      G[gb + 512 + li]      = c0 * uu0;
      G[gb + 512 + 16 + li] = c1 * uu1;
      hc0 += wgtRow[r] * c0;
      hc1 += wgtRow[r] * c1;
    }
    hc0 += __shfl_xor(hc0, 16); hc0 += __shfl_xor(hc0, 32);
    hc1 += __shfl_xor(hc1, 16); hc1 += __shfl_xor(hc1, 32);
    if (g == 0) {
      sHall[wv][32 * cc + li]      = hc0;
      sHall[wv][32 * cc + 16 + li] = hc1;
    }
  }

  // ---- hp2 write ----
  __syncthreads();
  float* hp = hp2 + (size_t)(b * 32 + tile) * 260;
  {
    const int d = tid & 255;
    float ph = sHall[0][d] + sHall[1][d] + sHall[2][d] + sHall[3][d];
    hp[d] = ph;
  }
  if (tid == 0) {
    hp[256] = Mloc;
    hp[257] = sRedZ[0] + sRedZ[1] + sRedZ[2] + sRedZ[3];
  }
  #undef STAGE
  #undef STAGE2
}

// K2h: per batch, combine 32 tile partials -> h[b][256]
__global__ __launch_bounds__(256) void k2h(const float* __restrict__ hp2,
                                           float* __restrict__ h_ws) {
  __shared__ float sM2[32], sZ2[32];
  const int b = blockIdx.x;
  const int tid = threadIdx.x;
  if (tid < 32) {
    sM2[tid] = hp2[(size_t)(b * 32 + tid) * 260 + 256];
    sZ2[tid] = hp2[(size_t)(b * 32 + tid) * 260 + 257];
  }
  __syncthreads();
  float M = -1e30f;
  #pragma unroll
  for (int i = 0; i < 32; ++i) M = fmaxf(M, sM2[i]);
  float Z = 0.f;
  float a = 0.f;
  #pragma unroll
  for (int i = 0; i < 32; ++i) {
    float e = __expf(sM2[i] - M);
    Z += sZ2[i] * e;
    a += hp2[(size_t)(b * 32 + i) * 260 + tid] * e;
  }
  h_ws[b * 256 + tid] = a / Z;
}

// K3: G[...,768:1024] = C * h[b,:]
__global__ __launch_bounds__(256) void k3_epi(const float* __restrict__ ctx,
                                              const float* __restrict__ h_ws,
                                              float* __restrict__ G) {
  size_t f = (size_t)blockIdx.x * 256 + threadIdx.x;
  size_t e = f * 4;
  int d = (int)(e & 255);
  size_t bt = e >> 8;
  int b = (int)(bt >> 11);
  float4 c = *(const float4*)(ctx + e);
  float4 h = *(const float4*)(h_ws + b * ND + d);
  *(float4*)(G + bt * 1024 + 768 + d) =
      make_float4(c.x * h.x, c.y * h.y, c.z * h.z, c.w * h.w);
}

extern "C" void kernel_launch(void* const* d_in, const int* in_sizes, int n_in,
                              void* d_out, int out_size, void* d_ws, size_t ws_size,
                              hipStream_t stream) {
  const float* ctx = (const float*)d_in[0];
  const float* qry = (const float*)d_in[1];
  const float* w   = (const float*)d_in[2];
  float* G  = (float*)d_out;
  float* ws = (float*)d_ws;
  float* hp2   = ws + HP2_OFF;
  float* h_ws  = ws + H_OFF;
  float* q2_ws = ws + Q2_OFF;
  short* Qbf = (short*)(ws + QBF_OFF);
  short* Qt  = (short*)(ws + QT_OFF);

  k0_prep<<<NB * 8, 256, 0, stream>>>(qry, w, q2_ws, Qbf, Qt);
  k1_main<<<NB * (NTC / 64), 256, 0, stream>>>(ctx, w, Qbf, Qt, q2_ws, hp2, G);
  k2h<<<NB, 256, 0, stream>>>(hp2, h_ws);
  k3_epi<<<16384, 256, 0, stream>>>(ctx, h_ws, G);
}